// Round 2
// baseline (2657.484 us; speedup 1.0000x reference)
//
#include <hip/hip_runtime.h>

#define N_ROWS 32768   // BS*SEQ
#define N_CODES 8192
#define DIM 256
#define TWO_EPS 2e-5f

typedef __attribute__((ext_vector_type(8))) short bf16x8;
typedef __attribute__((ext_vector_type(4))) float f32x4;
typedef __attribute__((ext_vector_type(8))) unsigned short u16x8;

#define GLOAD_LDS16(gp, lp) __builtin_amdgcn_global_load_lds( \
    (const __attribute__((address_space(1))) void*)(gp), \
    (__attribute__((address_space(3))) void*)(lp), 16, 0, 0)

__device__ __forceinline__ unsigned short f2bf_rne(float f) {
    unsigned int u = __float_as_uint(f);
    unsigned int r = (u + 0x7FFFu + ((u >> 16) & 1u)) >> 16;
    return (unsigned short)r;
}
__device__ __forceinline__ float bf2f(unsigned short h) {
    return __uint_as_float(((unsigned int)h) << 16);
}

// ---------------- split fp32 -> (hi, lo) bf16 ----------------
__global__ void split_kernel(const float* __restrict__ src,
                             unsigned short* __restrict__ hi,
                             unsigned short* __restrict__ lo) {
    size_t i = ((size_t)blockIdx.x * blockDim.x + threadIdx.x) * 8;
    float4 v0 = *reinterpret_cast<const float4*>(src + i);
    float4 v1 = *reinterpret_cast<const float4*>(src + i + 4);
    float f[8] = {v0.x, v0.y, v0.z, v0.w, v1.x, v1.y, v1.z, v1.w};
    u16x8 h, l;
    #pragma unroll
    for (int j = 0; j < 8; ++j) {
        unsigned short hb = f2bf_rne(f[j]);
        h[j] = hb;
        l[j] = f2bf_rne(f[j] - bf2f(hb));
    }
    *reinterpret_cast<u16x8*>(hi + i) = h;
    *reinterpret_cast<u16x8*>(lo + i) = l;
}

// ---------------- c_sq: one wave per code (round-1, verified) ----------------
__global__ void csq_kernel(const float* __restrict__ C, float* __restrict__ csq) {
    int gtid = blockIdx.x * blockDim.x + threadIdx.x;
    int wave = gtid >> 6;
    int lane = threadIdx.x & 63;
    float4 v = reinterpret_cast<const float4*>(C + (size_t)wave * DIM)[lane];
    float s = v.x * v.x + v.y * v.y + v.z * v.z + v.w * v.w;
    #pragma unroll
    for (int m = 32; m; m >>= 1) s += __shfl_xor(s, m);
    if (lane == 0) csq[wave] = s;
}

__global__ void init_kernel(int* count) { *count = 0; }

// ---------------- phase 1: bf16-split MFMA GEMM + fused top-2 ----------------
// grid = 2048 = 256 rowblocks x 8 codeblocks (blockIdx%8 -> XCD slot)
// block = 256 thr = 4 waves (2x2), tile 128 rows x 128 codes, virtual K = 768
__global__ __launch_bounds__(256, 2) void gemm_argmin_kernel(
        const unsigned short* __restrict__ xh, const unsigned short* __restrict__ xl,
        const unsigned short* __restrict__ ch, const unsigned short* __restrict__ cl,
        const float* __restrict__ csq, float* __restrict__ partials) {
    __shared__ unsigned short As[128 * 32];   // [128 rows][32 k] 8 KB
    __shared__ unsigned short Bs[128 * 32];   // [128 codes][32 k] 8 KB

    const int tid  = threadIdx.x;
    const int w    = tid >> 6;
    const int lane = tid & 63;
    const int wr = w >> 1, wc = w & 1;
    const int lcol = lane & 15, lkhi = lane >> 4;

    const int rowblk = blockIdx.x >> 3;
    const int cb     = blockIdx.x & 7;
    const int rowbase = rowblk * 128;

    // staging geometry: wave w owns LDS chunks w2 = 2w, 2w+1 of each tile.
    // lane l -> LDS byte w2*1024 + l*16 -> row w2*16 + (l>>2), k = (l&3)*8
    const int st_row = (lane >> 2);
    const int st_k   = (lane & 3) * 8;

    float v1[16], v2[16]; int i1[16];
    #pragma unroll
    for (int s = 0; s < 16; ++s) { v1[s] = 3.4e38f; v2[s] = 3.4e38f; i1[s] = 0x7fffffff; }

    for (int t = 0; t < 8; ++t) {
        const int codebase = cb * 1024 + t * 128;
        f32x4 acc[4][4];
        #pragma unroll
        for (int m = 0; m < 4; ++m)
            #pragma unroll
            for (int n = 0; n < 4; ++n) acc[m][n] = (f32x4){0.f, 0.f, 0.f, 0.f};

        for (int kk = 0; kk < 24; ++kk) {
            const int seg = kk >> 3;
            const int k0  = (kk & 7) * 32;
            const unsigned short* Aseg = (seg == 1) ? xl : xh;
            const unsigned short* Bseg = (seg == 2) ? cl : ch;

            #pragma unroll
            for (int c = 0; c < 2; ++c) {
                const int w2 = w * 2 + c;
                const unsigned short* ga = Aseg +
                    (size_t)(rowbase + w2 * 16 + st_row) * DIM + k0 + st_k;
                GLOAD_LDS16(ga, &As[w2 * 512]);
                const unsigned short* gb = Bseg +
                    (size_t)(codebase + w2 * 16 + st_row) * DIM + k0 + st_k;
                GLOAD_LDS16(gb, &Bs[w2 * 512]);
            }
            __syncthreads();

            bf16x8 a[4], b[4];
            #pragma unroll
            for (int m = 0; m < 4; ++m)
                a[m] = *reinterpret_cast<const bf16x8*>(
                    &As[(wr * 64 + m * 16 + lcol) * 32 + lkhi * 8]);
            #pragma unroll
            for (int n = 0; n < 4; ++n)
                b[n] = *reinterpret_cast<const bf16x8*>(
                    &Bs[(wc * 64 + n * 16 + lcol) * 32 + lkhi * 8]);
            #pragma unroll
            for (int m = 0; m < 4; ++m)
                #pragma unroll
                for (int n = 0; n < 4; ++n)
                    acc[m][n] = __builtin_amdgcn_mfma_f32_16x16x32_bf16(
                        a[m], b[n], acc[m][n], 0, 0, 0);
            __syncthreads();
        }

        // epilogue: dist = csq - 2*dot, branchless per-lane top-2
        #pragma unroll
        for (int n = 0; n < 4; ++n) {
            const int code = codebase + wc * 64 + n * 16 + lcol;
            const float cs = csq[code];
            #pragma unroll
            for (int m = 0; m < 4; ++m) {
                #pragma unroll
                for (int r = 0; r < 4; ++r) {
                    const int s = m * 4 + r;
                    float d = fmaf(-2.0f, acc[m][n][r], cs);
                    float vmax = fmaxf(d, v1[s]);
                    v2[s] = fminf(v2[s], vmax);
                    bool lt = d < v1[s];
                    v1[s] = lt ? d : v1[s];
                    i1[s] = lt ? code : i1[s];
                }
            }
        }
    }

    // merge top-2 across the 16 lanes sharing each physical row
    #pragma unroll
    for (int mask = 1; mask < 16; mask <<= 1) {
        #pragma unroll
        for (int s = 0; s < 16; ++s) {
            float ov1 = __shfl_xor(v1[s], mask);
            float ov2 = __shfl_xor(v2[s], mask);
            int   oi1 = __shfl_xor(i1[s], mask);
            float nv2 = fminf(fminf(v2[s], ov2), fmaxf(v1[s], ov1));
            bool take = (ov1 < v1[s]) || (ov1 == v1[s] && oi1 < i1[s]);
            v1[s] = take ? ov1 : v1[s];
            i1[s] = take ? oi1 : i1[s];
            v2[s] = nv2;
        }
    }

    // lane g*16 + s writes slot s (m = s>>2, r = s&3) for row group g
    const int g = lkhi;
    const int slot = cb * 2 + wc;
    #pragma unroll
    for (int s = 0; s < 16; ++s) {
        if (lcol == s) {
            int row = rowbase + wr * 64 + (s >> 2) * 16 + g * 4 + (s & 3);
            float4 p = make_float4(v1[s], v2[s], __int_as_float(i1[s]), 0.f);
            *reinterpret_cast<float4*>(&partials[((size_t)row * 16 + slot) * 4]) = p;
        }
    }
}

// ---------------- reduce 16 partial slots per row -> idx or flag ----------------
__global__ void reduce_kernel(const float* __restrict__ partials,
                              int* __restrict__ idx,
                              int* __restrict__ flaglist, int* __restrict__ count) {
    int row = blockIdx.x * 256 + threadIdx.x;
    float v1 = 3.4e38f, v2 = 3.4e38f; int i1 = 0x7fffffff;
    #pragma unroll
    for (int s = 0; s < 16; ++s) {
        float4 p = *reinterpret_cast<const float4*>(&partials[((size_t)row * 16 + s) * 4]);
        float sv1 = p.x, sv2 = p.y; int si1 = __float_as_int(p.z);
        float nv2 = fminf(fminf(v2, sv2), fmaxf(v1, sv1));
        bool take = (sv1 < v1) || (sv1 == v1 && si1 < i1);
        i1 = take ? si1 : i1;
        v1 = fminf(v1, sv1);
        v2 = nv2;
    }
    if (v2 - v1 > TWO_EPS) {
        idx[row] = i1;
    } else {
        int p = atomicAdd(count, 1);
        flaglist[p] = row;
    }
}

// ---------------- exact fp32 recheck for flagged rows (one wave per row) -----
__global__ __launch_bounds__(256) void recheck_kernel(
        const float* __restrict__ X, const float* __restrict__ C,
        const float* __restrict__ csq, const int* __restrict__ flaglist,
        const int* __restrict__ count, int* __restrict__ idx) {
    const int nf = *count;
    const int lane = threadIdx.x & 63;
    const int gwave = (blockIdx.x * 256 + threadIdx.x) >> 6;
    const int nwaves = gridDim.x * 4;
    for (int i = gwave; i < nf; i += nwaves) {
        const int row = flaglist[i];
        float4 xv = reinterpret_cast<const float4*>(X + (size_t)row * DIM)[lane];
        float best = 3.4e38f; int bi = 0;
        for (int c = 0; c < N_CODES; c += 2) {
            float4 c0 = reinterpret_cast<const float4*>(C + (size_t)c * DIM)[lane];
            float4 c1 = reinterpret_cast<const float4*>(C + (size_t)(c + 1) * DIM)[lane];
            float p0 = xv.x * c0.x + xv.y * c0.y + xv.z * c0.z + xv.w * c0.w;
            float p1 = xv.x * c1.x + xv.y * c1.y + xv.z * c1.z + xv.w * c1.w;
            #pragma unroll
            for (int m = 1; m < 64; m <<= 1) {
                p0 += __shfl_xor(p0, m);
                p1 += __shfl_xor(p1, m);
            }
            float d0 = fmaf(-2.0f, p0, csq[c]);
            float d1 = fmaf(-2.0f, p1, csq[c + 1]);
            if (d0 < best) { best = d0; bi = c; }
            if (d1 < best) { best = d1; bi = c + 1; }
        }
        if (lane == 0) idx[row] = bi;
    }
}

// ---------------- gather: one wave per row, write both halves (round-1) ------
__global__ void gather_kernel(const float* __restrict__ C,
                              const int* __restrict__ idx,
                              float* __restrict__ out) {
    const size_t half = (size_t)N_ROWS * DIM;
    int gtid = blockIdx.x * blockDim.x + threadIdx.x;
    int lane = threadIdx.x & 63;
    int wave = gtid >> 6;
    int nwaves = (gridDim.x * blockDim.x) >> 6;
    for (int row = wave; row < N_ROWS; row += nwaves) {
        int id = idx[row];
        float4 v = reinterpret_cast<const float4*>(C + (size_t)id * DIM)[lane];
        reinterpret_cast<float4*>(out + (size_t)row * DIM)[lane] = v;
        reinterpret_cast<float4*>(out + half + (size_t)row * DIM)[lane] = v;
    }
}

extern "C" void kernel_launch(void* const* d_in, const int* in_sizes, int n_in,
                              void* d_out, int out_size, void* d_ws, size_t ws_size,
                              hipStream_t stream) {
    const float* z  = (const float*)d_in[0];   // (32,1024,256) fp32
    const float* cb = (const float*)d_in[1];   // (8192,256)    fp32
    float* out = (float*)d_out;

    // big scratch lives in d_out (fully overwritten by gather at the end):
    char* sc = (char*)d_out;
    unsigned short* xh = (unsigned short*)(sc);               // 16,777,216 B
    unsigned short* xl = (unsigned short*)(sc + 16777216);    // 16,777,216 B
    unsigned short* chh = (unsigned short*)(sc + 33554432);   //  4,194,304 B
    unsigned short* cll = (unsigned short*)(sc + 37748736);   //  4,194,304 B
    float* partials     = (float*)(sc + 41943040);            //  8,388,608 B

    // small scratch in d_ws (~295 KB):
    float* csq    = (float*)d_ws;                              // 32 KB
    int*   idx    = (int*)((char*)d_ws + 32768);               // 128 KB
    int*   flags  = (int*)((char*)d_ws + 163840);              // 128 KB
    int*   count  = (int*)((char*)d_ws + 294912);              // 4 B

    init_kernel<<<1, 1, 0, stream>>>(count);
    split_kernel<<<(N_ROWS * DIM) / (256 * 8), 256, 0, stream>>>(z, xh, xl);
    split_kernel<<<(N_CODES * DIM) / (256 * 8), 256, 0, stream>>>(cb, chh, cll);
    csq_kernel<<<(N_CODES * 64) / 256, 256, 0, stream>>>(cb, csq);
    gemm_argmin_kernel<<<2048, 256, 0, stream>>>(xh, xl, chh, cll, csq, partials);
    reduce_kernel<<<N_ROWS / 256, 256, 0, stream>>>(partials, idx, flags, count);
    recheck_kernel<<<512, 256, 0, stream>>>(z, cb, csq, flags, count, idx);
    gather_kernel<<<2048, 256, 0, stream>>>(cb, idx, out);
}

// Round 3
// 890.550 us; speedup vs baseline: 2.9841x; 2.9841x over previous
//
#include <hip/hip_runtime.h>

#define N_ROWS 32768   // BS*SEQ
#define N_CODES 8192
#define DIM 256
#define TWO_EPS 4e-6f  // > 2x sup error bound (~1.5e-6) of bf16-split distance

typedef __attribute__((ext_vector_type(8))) short bf16x8;
typedef __attribute__((ext_vector_type(4))) float f32x4;
typedef __attribute__((ext_vector_type(8))) unsigned short u16x8;

#define GLOAD_LDS16(gp, lp) __builtin_amdgcn_global_load_lds( \
    (const __attribute__((address_space(1))) void*)(gp), \
    (__attribute__((address_space(3))) void*)(lp), 16, 0, 0)

__device__ __forceinline__ unsigned short f2bf_rne(float f) {
    unsigned int u = __float_as_uint(f);
    unsigned int r = (u + 0x7FFFu + ((u >> 16) & 1u)) >> 16;
    return (unsigned short)r;
}
__device__ __forceinline__ float bf2f(unsigned short h) {
    return __uint_as_float(((unsigned int)h) << 16);
}

// ---------------- split fp32 -> (hi, lo) bf16 ----------------
__global__ void split_kernel(const float* __restrict__ src,
                             unsigned short* __restrict__ hi,
                             unsigned short* __restrict__ lo) {
    size_t i = ((size_t)blockIdx.x * blockDim.x + threadIdx.x) * 8;
    float4 v0 = *reinterpret_cast<const float4*>(src + i);
    float4 v1 = *reinterpret_cast<const float4*>(src + i + 4);
    float f[8] = {v0.x, v0.y, v0.z, v0.w, v1.x, v1.y, v1.z, v1.w};
    u16x8 h, l;
    #pragma unroll
    for (int j = 0; j < 8; ++j) {
        unsigned short hb = f2bf_rne(f[j]);
        h[j] = hb;
        l[j] = f2bf_rne(f[j] - bf2f(hb));
    }
    *reinterpret_cast<u16x8*>(hi + i) = h;
    *reinterpret_cast<u16x8*>(lo + i) = l;
}

// ---------------- c_sq: one wave per code ----------------
__global__ void csq_kernel(const float* __restrict__ C, float* __restrict__ csq) {
    int gtid = blockIdx.x * blockDim.x + threadIdx.x;
    int wave = gtid >> 6;
    int lane = threadIdx.x & 63;
    float4 v = reinterpret_cast<const float4*>(C + (size_t)wave * DIM)[lane];
    float s = v.x * v.x + v.y * v.y + v.z * v.z + v.w * v.w;
    #pragma unroll
    for (int m = 32; m; m >>= 1) s += __shfl_xor(s, m);
    if (lane == 0) csq[wave] = s;
}

__global__ void init_kernel(int* count) { *count = 0; }

// ---------------- phase 1: bf16-split MFMA GEMM + fused top-2 ----------------
__global__ __launch_bounds__(256, 2) void gemm_argmin_kernel(
        const unsigned short* __restrict__ xh, const unsigned short* __restrict__ xl,
        const unsigned short* __restrict__ ch, const unsigned short* __restrict__ cl,
        const float* __restrict__ csq, float* __restrict__ partials) {
    __shared__ unsigned short As[128 * 32];   // [128 rows][32 k] 8 KB
    __shared__ unsigned short Bs[128 * 32];   // [128 codes][32 k] 8 KB

    const int tid  = threadIdx.x;
    const int w    = tid >> 6;
    const int lane = tid & 63;
    const int wr = w >> 1, wc = w & 1;
    const int lcol = lane & 15, lkhi = lane >> 4;

    const int rowblk = blockIdx.x >> 3;
    const int cb     = blockIdx.x & 7;
    const int rowbase = rowblk * 128;

    const int st_row = (lane >> 2);
    const int st_k   = (lane & 3) * 8;

    float v1[16], v2[16]; int i1[16];
    #pragma unroll
    for (int s = 0; s < 16; ++s) { v1[s] = 3.4e38f; v2[s] = 3.4e38f; i1[s] = 0x7fffffff; }

    for (int t = 0; t < 8; ++t) {
        const int codebase = cb * 1024 + t * 128;
        f32x4 acc[4][4];
        #pragma unroll
        for (int m = 0; m < 4; ++m)
            #pragma unroll
            for (int n = 0; n < 4; ++n) acc[m][n] = (f32x4){0.f, 0.f, 0.f, 0.f};

        for (int kk = 0; kk < 24; ++kk) {
            const int seg = kk >> 3;
            const int k0  = (kk & 7) * 32;
            const unsigned short* Aseg = (seg == 1) ? xl : xh;
            const unsigned short* Bseg = (seg == 2) ? cl : ch;

            #pragma unroll
            for (int c = 0; c < 2; ++c) {
                const int w2 = w * 2 + c;
                const unsigned short* ga = Aseg +
                    (size_t)(rowbase + w2 * 16 + st_row) * DIM + k0 + st_k;
                GLOAD_LDS16(ga, &As[w2 * 512]);
                const unsigned short* gb = Bseg +
                    (size_t)(codebase + w2 * 16 + st_row) * DIM + k0 + st_k;
                GLOAD_LDS16(gb, &Bs[w2 * 512]);
            }
            __syncthreads();

            bf16x8 a[4], b[4];
            #pragma unroll
            for (int m = 0; m < 4; ++m)
                a[m] = *reinterpret_cast<const bf16x8*>(
                    &As[(wr * 64 + m * 16 + lcol) * 32 + lkhi * 8]);
            #pragma unroll
            for (int n = 0; n < 4; ++n)
                b[n] = *reinterpret_cast<const bf16x8*>(
                    &Bs[(wc * 64 + n * 16 + lcol) * 32 + lkhi * 8]);
            #pragma unroll
            for (int m = 0; m < 4; ++m)
                #pragma unroll
                for (int n = 0; n < 4; ++n)
                    acc[m][n] = __builtin_amdgcn_mfma_f32_16x16x32_bf16(
                        a[m], b[n], acc[m][n], 0, 0, 0);
            __syncthreads();
        }

        #pragma unroll
        for (int n = 0; n < 4; ++n) {
            const int code = codebase + wc * 64 + n * 16 + lcol;
            const float cs = csq[code];
            #pragma unroll
            for (int m = 0; m < 4; ++m) {
                #pragma unroll
                for (int r = 0; r < 4; ++r) {
                    const int s = m * 4 + r;
                    float d = fmaf(-2.0f, acc[m][n][r], cs);
                    float vmax = fmaxf(d, v1[s]);
                    v2[s] = fminf(v2[s], vmax);
                    bool lt = d < v1[s];
                    v1[s] = lt ? d : v1[s];
                    i1[s] = lt ? code : i1[s];
                }
            }
        }
    }

    #pragma unroll
    for (int mask = 1; mask < 16; mask <<= 1) {
        #pragma unroll
        for (int s = 0; s < 16; ++s) {
            float ov1 = __shfl_xor(v1[s], mask);
            float ov2 = __shfl_xor(v2[s], mask);
            int   oi1 = __shfl_xor(i1[s], mask);
            float nv2 = fminf(fminf(v2[s], ov2), fmaxf(v1[s], ov1));
            bool take = (ov1 < v1[s]) || (ov1 == v1[s] && oi1 < i1[s]);
            v1[s] = take ? ov1 : v1[s];
            i1[s] = take ? oi1 : i1[s];
            v2[s] = nv2;
        }
    }

    const int g = lkhi;
    const int slot = cb * 2 + wc;
    #pragma unroll
    for (int s = 0; s < 16; ++s) {
        if (lcol == s) {
            int row = rowbase + wr * 64 + (s >> 2) * 16 + g * 4 + (s & 3);
            float4 p = make_float4(v1[s], v2[s], __int_as_float(i1[s]), 0.f);
            *reinterpret_cast<float4*>(&partials[((size_t)row * 16 + slot) * 4]) = p;
        }
    }
}

// ---------------- reduce 16 partial slots per row -> idx or flag -------------
__global__ void reduce_kernel(const float* __restrict__ partials,
                              int* __restrict__ idx,
                              int* __restrict__ flaglist, int* __restrict__ count) {
    int row = blockIdx.x * 256 + threadIdx.x;
    float v1 = 3.4e38f, v2 = 3.4e38f; int i1 = 0x7fffffff;
    #pragma unroll
    for (int s = 0; s < 16; ++s) {
        float4 p = *reinterpret_cast<const float4*>(&partials[((size_t)row * 16 + s) * 4]);
        float sv1 = p.x, sv2 = p.y; int si1 = __float_as_int(p.z);
        float nv2 = fminf(fminf(v2, sv2), fmaxf(v1, sv1));
        bool take = (sv1 < v1) || (sv1 == v1 && si1 < i1);
        i1 = take ? si1 : i1;
        v1 = fminf(v1, sv1);
        v2 = nv2;
    }
    if (v2 - v1 > TWO_EPS) {
        idx[row] = i1;
    } else {
        int p = atomicAdd(count, 1);
        flaglist[p] = row;
    }
}

// ---------------- exact fp32 recheck: one BLOCK per flagged row --------------
// Per-thread serial ascending-d fp32 dot = round-1-validated summation order.
__global__ __launch_bounds__(256) void recheck_kernel(
        const float* __restrict__ X, const float* __restrict__ C,
        const float* __restrict__ csq, const int* __restrict__ flaglist,
        const int* __restrict__ count, int* __restrict__ idx) {
    __shared__ __align__(16) float xs[DIM];
    __shared__ float rv[4];
    __shared__ int   ri[4];
    const int nf = *count;
    const int tid = threadIdx.x;

    for (int b = blockIdx.x; b < nf; b += gridDim.x) {
        const int row = flaglist[b];
        __syncthreads();   // protect xs/rv/ri against previous iteration
        if (tid < 64)
            reinterpret_cast<float4*>(xs)[tid] =
                reinterpret_cast<const float4*>(X + (size_t)row * DIM)[tid];
        __syncthreads();

        float best = 3.4e38f; int bi = 0x7fffffff;
        for (int j = 0; j < 32; j += 2) {           // 2 codes per iter for ILP
            const int c0 = tid + j * 256;
            const int c1 = c0 + 256;
            const float* p0 = C + (size_t)c0 * DIM;
            const float* p1 = C + (size_t)c1 * DIM;
            float d0 = 0.f, d1 = 0.f;
            #pragma unroll 8
            for (int d = 0; d < DIM; d += 4) {
                float4 a  = *reinterpret_cast<const float4*>(xs + d);
                float4 q0 = *reinterpret_cast<const float4*>(p0 + d);
                float4 q1 = *reinterpret_cast<const float4*>(p1 + d);
                d0 = fmaf(a.x, q0.x, d0); d0 = fmaf(a.y, q0.y, d0);
                d0 = fmaf(a.z, q0.z, d0); d0 = fmaf(a.w, q0.w, d0);
                d1 = fmaf(a.x, q1.x, d1); d1 = fmaf(a.y, q1.y, d1);
                d1 = fmaf(a.z, q1.z, d1); d1 = fmaf(a.w, q1.w, d1);
            }
            float dist0 = fmaf(-2.f, d0, csq[c0]);
            float dist1 = fmaf(-2.f, d1, csq[c1]);
            if (dist0 < best) { best = dist0; bi = c0; }
            if (dist1 < best) { best = dist1; bi = c1; }
        }

        // wave reduce (lowest-index tie-break)
        #pragma unroll
        for (int m = 1; m < 64; m <<= 1) {
            float ov = __shfl_xor(best, m);
            int   oi = __shfl_xor(bi, m);
            if (ov < best || (ov == best && oi < bi)) { best = ov; bi = oi; }
        }
        if ((tid & 63) == 0) { rv[tid >> 6] = best; ri[tid >> 6] = bi; }
        __syncthreads();
        if (tid == 0) {
            #pragma unroll
            for (int wv = 1; wv < 4; ++wv) {
                if (rv[wv] < best || (rv[wv] == best && ri[wv] < bi)) {
                    best = rv[wv]; bi = ri[wv];
                }
            }
            idx[row] = bi;
        }
    }
}

// ---------------- gather: one wave per row, write both halves ----------------
__global__ void gather_kernel(const float* __restrict__ C,
                              const int* __restrict__ idx,
                              float* __restrict__ out) {
    const size_t half = (size_t)N_ROWS * DIM;
    int gtid = blockIdx.x * blockDim.x + threadIdx.x;
    int lane = threadIdx.x & 63;
    int wave = gtid >> 6;
    int nwaves = (gridDim.x * blockDim.x) >> 6;
    for (int row = wave; row < N_ROWS; row += nwaves) {
        int id = idx[row];
        float4 v = reinterpret_cast<const float4*>(C + (size_t)id * DIM)[lane];
        reinterpret_cast<float4*>(out + (size_t)row * DIM)[lane] = v;
        reinterpret_cast<float4*>(out + half + (size_t)row * DIM)[lane] = v;
    }
}

extern "C" void kernel_launch(void* const* d_in, const int* in_sizes, int n_in,
                              void* d_out, int out_size, void* d_ws, size_t ws_size,
                              hipStream_t stream) {
    const float* z  = (const float*)d_in[0];   // (32,1024,256) fp32
    const float* cb = (const float*)d_in[1];   // (8192,256)    fp32
    float* out = (float*)d_out;

    // big scratch lives in d_out (fully overwritten by gather at the end):
    char* sc = (char*)d_out;
    unsigned short* xh = (unsigned short*)(sc);               // 16,777,216 B
    unsigned short* xl = (unsigned short*)(sc + 16777216);    // 16,777,216 B
    unsigned short* chh = (unsigned short*)(sc + 33554432);   //  4,194,304 B
    unsigned short* cll = (unsigned short*)(sc + 37748736);   //  4,194,304 B
    float* partials     = (float*)(sc + 41943040);            //  8,388,608 B

    // small scratch in d_ws (~295 KB):
    float* csq    = (float*)d_ws;                              // 32 KB
    int*   idx    = (int*)((char*)d_ws + 32768);               // 128 KB
    int*   flags  = (int*)((char*)d_ws + 163840);              // 128 KB
    int*   count  = (int*)((char*)d_ws + 294912);              // 4 B

    init_kernel<<<1, 1, 0, stream>>>(count);
    split_kernel<<<(N_ROWS * DIM) / (256 * 8), 256, 0, stream>>>(z, xh, xl);
    split_kernel<<<(N_CODES * DIM) / (256 * 8), 256, 0, stream>>>(cb, chh, cll);
    csq_kernel<<<(N_CODES * 64) / 256, 256, 0, stream>>>(cb, csq);
    gemm_argmin_kernel<<<2048, 256, 0, stream>>>(xh, xl, chh, cll, csq, partials);
    reduce_kernel<<<N_ROWS / 256, 256, 0, stream>>>(partials, idx, flags, count);
    recheck_kernel<<<512, 256, 0, stream>>>(z, cb, csq, flags, count, idx);
    gather_kernel<<<2048, 256, 0, stream>>>(cb, idx, out);
}

// Round 4
// 872.385 us; speedup vs baseline: 3.0462x; 1.0208x over previous
//
#include <hip/hip_runtime.h>

#define N_ROWS 32768   // BS*SEQ
#define N_CODES 8192
#define DIM 256
#define KV 512         // packed K per operand (hi || lo)
#define NSTEP 24       // virtual K = 768, BK = 32
#define TWO_EPS 4e-6f  // > 2x sup error bound (~1.5e-6) of bf16-split distance

typedef __attribute__((ext_vector_type(8))) short bf16x8;
typedef __attribute__((ext_vector_type(4))) float f32x4;
typedef __attribute__((ext_vector_type(8))) unsigned short u16x8;

#define GLOAD_LDS16(gp, lp) __builtin_amdgcn_global_load_lds( \
    (const __attribute__((address_space(1))) void*)(gp), \
    (__attribute__((address_space(3))) void*)(lp), 16, 0, 0)

__device__ __forceinline__ unsigned short f2bf_rne(float f) {
    unsigned int u = __float_as_uint(f);
    unsigned int r = (u + 0x7FFFu + ((u >> 16) & 1u)) >> 16;
    return (unsigned short)r;
}
__device__ __forceinline__ float bf2f(unsigned short h) {
    return __uint_as_float(((unsigned int)h) << 16);
}

// ---------------- split fp32 -> packed [hi(256) || lo(256)] bf16 -------------
__global__ void split_pack_kernel(const float* __restrict__ src,
                                  unsigned short* __restrict__ dst) {
    size_t i = ((size_t)blockIdx.x * blockDim.x + threadIdx.x) * 8;
    int row = (int)(i >> 8);
    int col = (int)(i & 255);
    float4 v0 = *reinterpret_cast<const float4*>(src + i);
    float4 v1 = *reinterpret_cast<const float4*>(src + i + 4);
    float f[8] = {v0.x, v0.y, v0.z, v0.w, v1.x, v1.y, v1.z, v1.w};
    u16x8 h, l;
    #pragma unroll
    for (int j = 0; j < 8; ++j) {
        unsigned short hb = f2bf_rne(f[j]);
        h[j] = hb;
        l[j] = f2bf_rne(f[j] - bf2f(hb));
    }
    *reinterpret_cast<u16x8*>(dst + (size_t)row * KV + col) = h;
    *reinterpret_cast<u16x8*>(dst + (size_t)row * KV + 256 + col) = l;
}

// ---------------- c_sq: one wave per code ----------------
__global__ void csq_kernel(const float* __restrict__ C, float* __restrict__ csq) {
    int gtid = blockIdx.x * blockDim.x + threadIdx.x;
    int wave = gtid >> 6;
    int lane = threadIdx.x & 63;
    float4 v = reinterpret_cast<const float4*>(C + (size_t)wave * DIM)[lane];
    float s = v.x * v.x + v.y * v.y + v.z * v.z + v.w * v.w;
    #pragma unroll
    for (int m = 32; m; m >>= 1) s += __shfl_xor(s, m);
    if (lane == 0) csq[wave] = s;
}

__global__ void init_kernel(int* count) { *count = 0; }

__device__ __forceinline__ int AK0(int s) {
    return ((s >= 16) ? 256 : 0) + (s & 7) * 32;
}
__device__ __forceinline__ int BK0(int s) {
    return ((s >= 8 && s < 16) ? 256 : 0) + (s & 7) * 32;
}

// ---------------- phase 1: 256x256-tile bf16-split MFMA GEMM + top-2 ---------
// grid 4096 = 128 rowblocks x 32 codeblocks, 512 thr = 8 waves (2M x 4N)
__global__ __launch_bounds__(512, 2) void gemm_argmin_kernel(
        const unsigned short* __restrict__ A2,   // [32768][512]
        const unsigned short* __restrict__ B2,   // [8192][512]
        const float* __restrict__ csq,
        float4* __restrict__ partials) {         // [32 slots][32768 rows]
    __shared__ unsigned short S[32768];          // 64 KB: A dbuf @0, B dbuf @16384

    const int tid  = threadIdx.x;
    const int w    = tid >> 6;
    const int l    = tid & 63;
    const int wrM  = w >> 2;        // 0..1  -> rows [wrM*128, +128)
    const int wcN  = w & 3;         // 0..3  -> codes [wcN*64, +64)
    const int lcol = l & 15;
    const int g    = l >> 4;

    // bijective XCD swizzle: 4096 wg, 512 per XCD; rb fast (B slice L2-resident)
    const int swz = (blockIdx.x & 7) * 512 + (blockIdx.x >> 3);
    const int rb  = swz & 127;
    const int cbI = swz >> 7;
    const int rowbase  = rb * 256;
    const int codebase = cbI * 256;

    // staging: wave w stages A chunks {2w,2w+1} and B chunks {2w,2w+1}
    // chunk c = 1KB = 16 rows x 32 k;  lane l -> row c*16 + (l>>2), col (l&3)*8
    const int stRow = (l >> 2);
    const int stCol = (l & 3) * 8;

    f32x4 acc[8][4];
    #pragma unroll
    for (int m = 0; m < 8; ++m)
        #pragma unroll
        for (int n = 0; n < 4; ++n) acc[m][n] = (f32x4){0.f, 0.f, 0.f, 0.f};

    // prologue: stage tile 0 into buf 0
    {
        const int ak = AK0(0), bk = BK0(0);
        #pragma unroll
        for (int c2 = 0; c2 < 2; ++c2) {
            const int c = 2 * w + c2;
            GLOAD_LDS16(A2 + (size_t)(rowbase + c * 16 + stRow) * KV + ak + stCol,
                        &S[c * 512]);
            GLOAD_LDS16(B2 + (size_t)(codebase + c * 16 + stRow) * KV + bk + stCol,
                        &S[16384 + c * 512]);
        }
    }

    #pragma unroll 1
    for (int s = 0; s < NSTEP; ++s) {
        const int cur = s & 1;
        const int nxt = cur ^ 1;
        int sn = s + 1; if (sn == NSTEP) sn = 0;   // wrap: harmless dead stage
        const int ak = AK0(sn), bk = BK0(sn);
        #pragma unroll
        for (int c2 = 0; c2 < 2; ++c2) {
            const int c = 2 * w + c2;
            GLOAD_LDS16(A2 + (size_t)(rowbase + c * 16 + stRow) * KV + ak + stCol,
                        &S[nxt * 8192 + c * 512]);
            GLOAD_LDS16(B2 + (size_t)(codebase + c * 16 + stRow) * KV + bk + stCol,
                        &S[16384 + nxt * 8192 + c * 512]);
        }
        // wait only for the PREVIOUS tile's 4 loads; keep the 4 new in flight
        asm volatile("s_waitcnt vmcnt(4)" ::: "memory");
        __builtin_amdgcn_s_barrier();
        asm volatile("" ::: "memory");
        __builtin_amdgcn_sched_barrier(0);

        const unsigned short* Ab = &S[cur * 8192];
        const unsigned short* Bb = &S[16384 + cur * 8192];
        bf16x8 a[8], b[4];
        #pragma unroll
        for (int m = 0; m < 8; ++m)
            a[m] = *reinterpret_cast<const bf16x8*>(
                &Ab[(wrM * 128 + m * 16 + lcol) * 32 + g * 8]);
        #pragma unroll
        for (int n = 0; n < 4; ++n)
            b[n] = *reinterpret_cast<const bf16x8*>(
                &Bb[(wcN * 64 + n * 16 + lcol) * 32 + g * 8]);
        __builtin_amdgcn_s_setprio(1);
        #pragma unroll
        for (int m = 0; m < 8; ++m)
            #pragma unroll
            for (int n = 0; n < 4; ++n)
                acc[m][n] = __builtin_amdgcn_mfma_f32_16x16x32_bf16(
                    a[m], b[n], acc[m][n], 0, 0, 0);
        __builtin_amdgcn_s_setprio(0);
        asm volatile("s_waitcnt lgkmcnt(0)" ::: "memory");
        __builtin_amdgcn_sched_barrier(0);
        __builtin_amdgcn_s_barrier();
        asm volatile("" ::: "memory");
    }

    // drain the wrap-staged loads before reusing LDS
    asm volatile("s_waitcnt vmcnt(0)" ::: "memory");
    __builtin_amdgcn_s_barrier();
    asm volatile("" ::: "memory");

    // ---- epilogue: dist = csq - 2*dot, top-2, fold across 4 N-waves in LDS
    float4* T = reinterpret_cast<float4*>(S);    // [256 rows][4 wc]
    #pragma unroll
    for (int m = 0; m < 8; ++m) {
        #pragma unroll
        for (int r = 0; r < 4; ++r) {
            float v1 = 3.4e38f, v2 = 3.4e38f; int i1 = 0x7fffffff;
            #pragma unroll
            for (int n = 0; n < 4; ++n) {
                int code = codebase + wcN * 64 + n * 16 + lcol;
                float d = fmaf(-2.0f, acc[m][n][r], csq[code]);
                float vmax = fmaxf(d, v1);
                v2 = fminf(v2, vmax);
                bool lt = d < v1;
                v1 = lt ? d : v1;
                i1 = lt ? code : i1;
            }
            #pragma unroll
            for (int mask = 1; mask < 16; mask <<= 1) {
                float ov1 = __shfl_xor(v1, mask);
                float ov2 = __shfl_xor(v2, mask);
                int   oi1 = __shfl_xor(i1, mask);
                float nv2 = fminf(fminf(v2, ov2), fmaxf(v1, ov1));
                bool take = (ov1 < v1) || (ov1 == v1 && oi1 < i1);
                v1 = take ? ov1 : v1;
                i1 = take ? oi1 : i1;
                v2 = nv2;
            }
            if (lcol == ((m * 4 + r) & 15)) {
                int rowL = wrM * 128 + m * 16 + g * 4 + r;
                T[rowL * 4 + wcN] = make_float4(v1, v2, __int_as_float(i1), 0.f);
            }
        }
    }
    __syncthreads();
    if (tid < 256) {
        float v1 = 3.4e38f, v2 = 3.4e38f; int i1 = 0x7fffffff;
        #pragma unroll
        for (int s2 = 0; s2 < 4; ++s2) {
            float4 p = T[tid * 4 + s2];
            int pi = __float_as_int(p.z);
            float nv2 = fminf(fminf(v2, p.y), fmaxf(v1, p.x));
            bool take = (p.x < v1) || (p.x == v1 && pi < i1);
            i1 = take ? pi : i1;
            v1 = fminf(v1, p.x);
            v2 = nv2;
        }
        partials[(size_t)cbI * N_ROWS + rowbase + tid] =
            make_float4(v1, v2, __int_as_float(i1), 0.f);
    }
}

// ---------------- reduce 32 slot-major partials per row -> idx or flag -------
__global__ void reduce_kernel(const float4* __restrict__ partials,
                              int* __restrict__ idx,
                              int* __restrict__ flaglist, int* __restrict__ count) {
    int row = blockIdx.x * 256 + threadIdx.x;
    float v1 = 3.4e38f, v2 = 3.4e38f; int i1 = 0x7fffffff;
    #pragma unroll
    for (int s = 0; s < 32; ++s) {
        float4 p = partials[(size_t)s * N_ROWS + row];
        int pi = __float_as_int(p.z);
        float nv2 = fminf(fminf(v2, p.y), fmaxf(v1, p.x));
        bool take = (p.x < v1) || (p.x == v1 && pi < i1);
        i1 = take ? pi : i1;
        v1 = fminf(v1, p.x);
        v2 = nv2;
    }
    if (v2 - v1 > TWO_EPS) {
        idx[row] = i1;
    } else {
        int p = atomicAdd(count, 1);
        flaglist[p] = row;
    }
}

// ---------------- exact fp32 recheck: one BLOCK per flagged row --------------
__global__ __launch_bounds__(256) void recheck_kernel(
        const float* __restrict__ X, const float* __restrict__ C,
        const float* __restrict__ csq, const int* __restrict__ flaglist,
        const int* __restrict__ count, int* __restrict__ idx) {
    __shared__ __align__(16) float xs[DIM];
    __shared__ float rv[4];
    __shared__ int   ri[4];
    const int nf = *count;
    const int tid = threadIdx.x;

    for (int b = blockIdx.x; b < nf; b += gridDim.x) {
        const int row = flaglist[b];
        __syncthreads();
        if (tid < 64)
            reinterpret_cast<float4*>(xs)[tid] =
                reinterpret_cast<const float4*>(X + (size_t)row * DIM)[tid];
        __syncthreads();

        float best = 3.4e38f; int bi = 0x7fffffff;
        for (int j = 0; j < 32; j += 2) {
            const int c0 = tid + j * 256;
            const int c1 = c0 + 256;
            const float* p0 = C + (size_t)c0 * DIM;
            const float* p1 = C + (size_t)c1 * DIM;
            float d0 = 0.f, d1 = 0.f;
            #pragma unroll 8
            for (int d = 0; d < DIM; d += 4) {
                float4 a  = *reinterpret_cast<const float4*>(xs + d);
                float4 q0 = *reinterpret_cast<const float4*>(p0 + d);
                float4 q1 = *reinterpret_cast<const float4*>(p1 + d);
                d0 = fmaf(a.x, q0.x, d0); d0 = fmaf(a.y, q0.y, d0);
                d0 = fmaf(a.z, q0.z, d0); d0 = fmaf(a.w, q0.w, d0);
                d1 = fmaf(a.x, q1.x, d1); d1 = fmaf(a.y, q1.y, d1);
                d1 = fmaf(a.z, q1.z, d1); d1 = fmaf(a.w, q1.w, d1);
            }
            float dist0 = fmaf(-2.f, d0, csq[c0]);
            float dist1 = fmaf(-2.f, d1, csq[c1]);
            if (dist0 < best) { best = dist0; bi = c0; }
            if (dist1 < best) { best = dist1; bi = c1; }
        }
        #pragma unroll
        for (int m = 1; m < 64; m <<= 1) {
            float ov = __shfl_xor(best, m);
            int   oi = __shfl_xor(bi, m);
            if (ov < best || (ov == best && oi < bi)) { best = ov; bi = oi; }
        }
        if ((tid & 63) == 0) { rv[tid >> 6] = best; ri[tid >> 6] = bi; }
        __syncthreads();
        if (tid == 0) {
            #pragma unroll
            for (int wv = 1; wv < 4; ++wv) {
                if (rv[wv] < best || (rv[wv] == best && ri[wv] < bi)) {
                    best = rv[wv]; bi = ri[wv];
                }
            }
            idx[row] = bi;
        }
    }
}

// ---------------- gather: one wave per row, write both halves ----------------
__global__ void gather_kernel(const float* __restrict__ C,
                              const int* __restrict__ idx,
                              float* __restrict__ out) {
    const size_t half = (size_t)N_ROWS * DIM;
    int gtid = blockIdx.x * blockDim.x + threadIdx.x;
    int lane = threadIdx.x & 63;
    int wave = gtid >> 6;
    int nwaves = (gridDim.x * blockDim.x) >> 6;
    for (int row = wave; row < N_ROWS; row += nwaves) {
        int id = idx[row];
        float4 v = reinterpret_cast<const float4*>(C + (size_t)id * DIM)[lane];
        reinterpret_cast<float4*>(out + (size_t)row * DIM)[lane] = v;
        reinterpret_cast<float4*>(out + half + (size_t)row * DIM)[lane] = v;
    }
}

extern "C" void kernel_launch(void* const* d_in, const int* in_sizes, int n_in,
                              void* d_out, int out_size, void* d_ws, size_t ws_size,
                              hipStream_t stream) {
    const float* z  = (const float*)d_in[0];   // (32,1024,256) fp32
    const float* cb = (const float*)d_in[1];   // (8192,256)    fp32
    float* out = (float*)d_out;

    // big scratch in d_out (fully overwritten by gather at the end):
    char* sc = (char*)d_out;
    unsigned short* A2 = (unsigned short*)(sc);               // 33,554,432 B
    unsigned short* B2 = (unsigned short*)(sc + 33554432);    //  8,388,608 B
    float4* partials   = (float4*)(sc + 41943040);            // 16,777,216 B

    // small scratch in d_ws (~295 KB):
    float* csq    = (float*)d_ws;                              // 32 KB
    int*   idx    = (int*)((char*)d_ws + 32768);               // 128 KB
    int*   flags  = (int*)((char*)d_ws + 163840);              // 128 KB
    int*   count  = (int*)((char*)d_ws + 294912);              // 4 B

    init_kernel<<<1, 1, 0, stream>>>(count);
    split_pack_kernel<<<(N_ROWS * DIM) / (256 * 8), 256, 0, stream>>>(z, A2);
    split_pack_kernel<<<(N_CODES * DIM) / (256 * 8), 256, 0, stream>>>(cb, B2);
    csq_kernel<<<(N_CODES * 64) / 256, 256, 0, stream>>>(cb, csq);
    gemm_argmin_kernel<<<4096, 512, 0, stream>>>(A2, B2, csq, partials);
    reduce_kernel<<<N_ROWS / 256, 256, 0, stream>>>(partials, idx, flags, count);
    recheck_kernel<<<512, 256, 0, stream>>>(z, cb, csq, flags, count, idx);
    gather_kernel<<<2048, 256, 0, stream>>>(cb, idx, out);
}

// Round 5
// 837.526 us; speedup vs baseline: 3.1730x; 1.0416x over previous
//
#include <hip/hip_runtime.h>

#define N_ROWS 32768   // BS*SEQ
#define N_CODES 8192
#define DIM 256
#define KV 512         // packed K per operand (hi || lo)
#define NSTEP 12       // virtual K = 768, BK = 64
#define TWO_EPS 4e-6f  // > 2x sup error bound (~1.5e-6) of bf16-split distance

typedef __attribute__((ext_vector_type(8))) short bf16x8;
typedef __attribute__((ext_vector_type(4))) float f32x4;
typedef __attribute__((ext_vector_type(8))) unsigned short u16x8;

#define GLOAD_LDS16(gp, lp) __builtin_amdgcn_global_load_lds( \
    (const __attribute__((address_space(1))) void*)(gp), \
    (__attribute__((address_space(3))) void*)(lp), 16, 0, 0)

__device__ __forceinline__ unsigned short f2bf_rne(float f) {
    unsigned int u = __float_as_uint(f);
    unsigned int r = (u + 0x7FFFu + ((u >> 16) & 1u)) >> 16;
    return (unsigned short)r;
}
__device__ __forceinline__ float bf2f(unsigned short h) {
    return __uint_as_float(((unsigned int)h) << 16);
}

// ---------------- split fp32 -> packed [hi(256) || lo(256)] bf16 -------------
__global__ void split_pack_kernel(const float* __restrict__ src,
                                  unsigned short* __restrict__ dst) {
    size_t i = ((size_t)blockIdx.x * blockDim.x + threadIdx.x) * 8;
    int row = (int)(i >> 8);
    int col = (int)(i & 255);
    float4 v0 = *reinterpret_cast<const float4*>(src + i);
    float4 v1 = *reinterpret_cast<const float4*>(src + i + 4);
    float f[8] = {v0.x, v0.y, v0.z, v0.w, v1.x, v1.y, v1.z, v1.w};
    u16x8 h, l;
    #pragma unroll
    for (int j = 0; j < 8; ++j) {
        unsigned short hb = f2bf_rne(f[j]);
        h[j] = hb;
        l[j] = f2bf_rne(f[j] - bf2f(hb));
    }
    *reinterpret_cast<u16x8*>(dst + (size_t)row * KV + col) = h;
    *reinterpret_cast<u16x8*>(dst + (size_t)row * KV + 256 + col) = l;
}

// ---------------- c_sq: one wave per code ----------------
__global__ void csq_kernel(const float* __restrict__ C, float* __restrict__ csq) {
    int gtid = blockIdx.x * blockDim.x + threadIdx.x;
    int wave = gtid >> 6;
    int lane = threadIdx.x & 63;
    float4 v = reinterpret_cast<const float4*>(C + (size_t)wave * DIM)[lane];
    float s = v.x * v.x + v.y * v.y + v.z * v.z + v.w * v.w;
    #pragma unroll
    for (int m = 32; m; m >>= 1) s += __shfl_xor(s, m);
    if (lane == 0) csq[wave] = s;
}

__global__ void init_kernel(int* count) { *count = 0; }

// K-offsets (shorts) into the packed [hi||lo] K=512 operands, BK=64:
// steps 0-3: hi.hi  4-7: hi(A).lo(B)  8-11: lo(A).hi(B)
__device__ __forceinline__ int AK0(int s) {
    return ((s >= 8) ? 256 : 0) + (s & 3) * 64;
}
__device__ __forceinline__ int BK0(int s) {
    return ((s >= 4 && s < 8) ? 256 : 0) + (s & 3) * 64;
}

// ---------------- phase 1: 256x256-tile, BK=64, swizzled-LDS MFMA GEMM -------
// grid 4096 = 128 rowblocks x 32 codeblocks, 512 thr = 8 waves (2M x 4N)
// LDS 128 KiB dynamic: A dbuf [2][16384] shorts @0, B dbuf @32768 shorts
__global__ __launch_bounds__(512, 2) void gemm_argmin_kernel(
        const unsigned short* __restrict__ A2,   // [32768][512]
        const unsigned short* __restrict__ B2,   // [8192][512]
        const float* __restrict__ csq,
        float4* __restrict__ partials) {         // [32 slots][32768 rows]
    extern __shared__ unsigned short S[];        // 131072 B

    const int tid  = threadIdx.x;
    const int w    = tid >> 6;
    const int l    = tid & 63;
    const int wrM  = w >> 2;        // 0..1  -> rows [wrM*128, +128)
    const int wcN  = w & 3;         // 0..3  -> codes [wcN*64, +64)
    const int lcol = l & 15;
    const int g    = l >> 4;

    // bijective XCD swizzle: 4096 wg, 512 per XCD; rb fast (B slice L2-resident)
    const int swz = (blockIdx.x & 7) * 512 + (blockIdx.x >> 3);
    const int rb  = swz & 127;
    const int cbI = swz >> 7;
    const int rowbase  = rb * 256;
    const int codebase = cbI * 256;

    // staging: chunk = 1 KB = 8 rows x 128 B. Wave w stages A chunks 4w..4w+3
    // and B chunks 4w..4w+3. LDS dest is linear (base + lane*16 by HW);
    // global source fetches k-slot (l&7)^(l>>3) so reads can swizzle.
    const int stRowIn = l >> 3;                  // row within chunk (0..7)
    const int stSwz   = (l & 7) ^ stRowIn;       // swizzled 16B k-slot

    f32x4 acc[8][4];
    #pragma unroll
    for (int m = 0; m < 8; ++m)
        #pragma unroll
        for (int n = 0; n < 4; ++n) acc[m][n] = (f32x4){0.f, 0.f, 0.f, 0.f};

    // prologue: stage tile 0 into buf 0
    {
        const int ak = AK0(0), bk = BK0(0);
        #pragma unroll
        for (int i = 0; i < 4; ++i) {
            const int c = 4 * w + i;
            GLOAD_LDS16(A2 + (size_t)(rowbase + c * 8 + stRowIn) * KV + ak + stSwz * 8,
                        &S[c * 512]);
            GLOAD_LDS16(B2 + (size_t)(codebase + c * 8 + stRowIn) * KV + bk + stSwz * 8,
                        &S[32768 + c * 512]);
        }
    }

    #pragma unroll 1
    for (int s = 0; s < NSTEP; ++s) {
        const int cur = s & 1;
        const int nxt = cur ^ 1;
        int sn = s + 1; if (sn == NSTEP) sn = 0;   // wrap: harmless dead stage
        const int ak = AK0(sn), bk = BK0(sn);
        #pragma unroll
        for (int i = 0; i < 4; ++i) {
            const int c = 4 * w + i;
            GLOAD_LDS16(A2 + (size_t)(rowbase + c * 8 + stRowIn) * KV + ak + stSwz * 8,
                        &S[nxt * 16384 + c * 512]);
            GLOAD_LDS16(B2 + (size_t)(codebase + c * 8 + stRowIn) * KV + bk + stSwz * 8,
                        &S[32768 + nxt * 16384 + c * 512]);
        }
        // wait only for the PREVIOUS tile's 8 loads; keep the new 8 in flight
        asm volatile("s_waitcnt vmcnt(8)" ::: "memory");
        __builtin_amdgcn_s_barrier();
        asm volatile("" ::: "memory");
        __builtin_amdgcn_sched_barrier(0);

        const unsigned short* Ab = &S[cur * 16384];
        const unsigned short* Bb = &S[32768 + cur * 16384];
        __builtin_amdgcn_s_setprio(1);
        #pragma unroll
        for (int kh = 0; kh < 2; ++kh) {
            bf16x8 a[8], b[4];
            #pragma unroll
            for (int m = 0; m < 8; ++m) {
                const int row = wrM * 128 + m * 16 + lcol;
                const int slot = ((kh << 2) | g) ^ (lcol & 7);
                a[m] = *reinterpret_cast<const bf16x8*>(&Ab[row * 64 + slot * 8]);
            }
            #pragma unroll
            for (int n = 0; n < 4; ++n) {
                const int row = wcN * 64 + n * 16 + lcol;
                const int slot = ((kh << 2) | g) ^ (lcol & 7);
                b[n] = *reinterpret_cast<const bf16x8*>(&Bb[row * 64 + slot * 8]);
            }
            #pragma unroll
            for (int m = 0; m < 8; ++m)
                #pragma unroll
                for (int n = 0; n < 4; ++n)
                    acc[m][n] = __builtin_amdgcn_mfma_f32_16x16x32_bf16(
                        a[m], b[n], acc[m][n], 0, 0, 0);
        }
        __builtin_amdgcn_s_setprio(0);
        asm volatile("s_waitcnt lgkmcnt(0)" ::: "memory");
        __builtin_amdgcn_sched_barrier(0);
        __builtin_amdgcn_s_barrier();
        asm volatile("" ::: "memory");
    }

    // drain the wrap-staged loads before reusing LDS
    asm volatile("s_waitcnt vmcnt(0)" ::: "memory");
    __builtin_amdgcn_s_barrier();
    asm volatile("" ::: "memory");

    // ---- epilogue: dist = csq - 2*dot, top-2, fold across 4 N-waves in LDS
    float4* T = reinterpret_cast<float4*>(S);    // [256 rows][4 wc]
    #pragma unroll
    for (int m = 0; m < 8; ++m) {
        #pragma unroll
        for (int r = 0; r < 4; ++r) {
            float v1 = 3.4e38f, v2 = 3.4e38f; int i1 = 0x7fffffff;
            #pragma unroll
            for (int n = 0; n < 4; ++n) {
                int code = codebase + wcN * 64 + n * 16 + lcol;
                float d = fmaf(-2.0f, acc[m][n][r], csq[code]);
                float vmax = fmaxf(d, v1);
                v2 = fminf(v2, vmax);
                bool lt = d < v1;
                v1 = lt ? d : v1;
                i1 = lt ? code : i1;
            }
            #pragma unroll
            for (int mask = 1; mask < 16; mask <<= 1) {
                float ov1 = __shfl_xor(v1, mask);
                float ov2 = __shfl_xor(v2, mask);
                int   oi1 = __shfl_xor(i1, mask);
                float nv2 = fminf(fminf(v2, ov2), fmaxf(v1, ov1));
                bool take = (ov1 < v1) || (ov1 == v1 && oi1 < i1);
                v1 = take ? ov1 : v1;
                i1 = take ? oi1 : i1;
                v2 = nv2;
            }
            if (lcol == ((m * 4 + r) & 15)) {
                int rowL = wrM * 128 + m * 16 + g * 4 + r;
                T[rowL * 4 + wcN] = make_float4(v1, v2, __int_as_float(i1), 0.f);
            }
        }
    }
    __syncthreads();
    if (tid < 256) {
        float v1 = 3.4e38f, v2 = 3.4e38f; int i1 = 0x7fffffff;
        #pragma unroll
        for (int s2 = 0; s2 < 4; ++s2) {
            float4 p = T[tid * 4 + s2];
            int pi = __float_as_int(p.z);
            float nv2 = fminf(fminf(v2, p.y), fmaxf(v1, p.x));
            bool take = (p.x < v1) || (p.x == v1 && pi < i1);
            i1 = take ? pi : i1;
            v1 = fminf(v1, p.x);
            v2 = nv2;
        }
        partials[(size_t)cbI * N_ROWS + rowbase + tid] =
            make_float4(v1, v2, __int_as_float(i1), 0.f);
    }
}

// ---------------- reduce 32 slot-major partials per row -> idx or flag -------
__global__ void reduce_kernel(const float4* __restrict__ partials,
                              int* __restrict__ idx,
                              int* __restrict__ flaglist, int* __restrict__ count) {
    int row = blockIdx.x * 256 + threadIdx.x;
    float v1 = 3.4e38f, v2 = 3.4e38f; int i1 = 0x7fffffff;
    #pragma unroll
    for (int s = 0; s < 32; ++s) {
        float4 p = partials[(size_t)s * N_ROWS + row];
        int pi = __float_as_int(p.z);
        float nv2 = fminf(fminf(v2, p.y), fmaxf(v1, p.x));
        bool take = (p.x < v1) || (p.x == v1 && pi < i1);
        i1 = take ? pi : i1;
        v1 = fminf(v1, p.x);
        v2 = nv2;
    }
    if (v2 - v1 > TWO_EPS) {
        idx[row] = i1;
    } else {
        int p = atomicAdd(count, 1);
        flaglist[p] = row;
    }
}

// ---------------- exact fp32 recheck: one BLOCK per flagged row --------------
__global__ __launch_bounds__(256) void recheck_kernel(
        const float* __restrict__ X, const float* __restrict__ C,
        const float* __restrict__ csq, const int* __restrict__ flaglist,
        const int* __restrict__ count, int* __restrict__ idx) {
    __shared__ __align__(16) float xs[DIM];
    __shared__ float rv[4];
    __shared__ int   ri[4];
    const int nf = *count;
    const int tid = threadIdx.x;

    for (int b = blockIdx.x; b < nf; b += gridDim.x) {
        const int row = flaglist[b];
        __syncthreads();
        if (tid < 64)
            reinterpret_cast<float4*>(xs)[tid] =
                reinterpret_cast<const float4*>(X + (size_t)row * DIM)[tid];
        __syncthreads();

        float best = 3.4e38f; int bi = 0x7fffffff;
        for (int j = 0; j < 32; j += 2) {
            const int c0 = tid + j * 256;
            const int c1 = c0 + 256;
            const float* p0 = C + (size_t)c0 * DIM;
            const float* p1 = C + (size_t)c1 * DIM;
            float d0 = 0.f, d1 = 0.f;
            #pragma unroll 8
            for (int d = 0; d < DIM; d += 4) {
                float4 a  = *reinterpret_cast<const float4*>(xs + d);
                float4 q0 = *reinterpret_cast<const float4*>(p0 + d);
                float4 q1 = *reinterpret_cast<const float4*>(p1 + d);
                d0 = fmaf(a.x, q0.x, d0); d0 = fmaf(a.y, q0.y, d0);
                d0 = fmaf(a.z, q0.z, d0); d0 = fmaf(a.w, q0.w, d0);
                d1 = fmaf(a.x, q1.x, d1); d1 = fmaf(a.y, q1.y, d1);
                d1 = fmaf(a.z, q1.z, d1); d1 = fmaf(a.w, q1.w, d1);
            }
            float dist0 = fmaf(-2.f, d0, csq[c0]);
            float dist1 = fmaf(-2.f, d1, csq[c1]);
            if (dist0 < best) { best = dist0; bi = c0; }
            if (dist1 < best) { best = dist1; bi = c1; }
        }
        #pragma unroll
        for (int m = 1; m < 64; m <<= 1) {
            float ov = __shfl_xor(best, m);
            int   oi = __shfl_xor(bi, m);
            if (ov < best || (ov == best && oi < bi)) { best = ov; bi = oi; }
        }
        if ((tid & 63) == 0) { rv[tid >> 6] = best; ri[tid >> 6] = bi; }
        __syncthreads();
        if (tid == 0) {
            #pragma unroll
            for (int wv = 1; wv < 4; ++wv) {
                if (rv[wv] < best || (rv[wv] == best && ri[wv] < bi)) {
                    best = rv[wv]; bi = ri[wv];
                }
            }
            idx[row] = bi;
        }
    }
}

// ---------------- gather: one wave per row, write both halves ----------------
__global__ void gather_kernel(const float* __restrict__ C,
                              const int* __restrict__ idx,
                              float* __restrict__ out) {
    const size_t half = (size_t)N_ROWS * DIM;
    int gtid = blockIdx.x * blockDim.x + threadIdx.x;
    int lane = threadIdx.x & 63;
    int wave = gtid >> 6;
    int nwaves = (gridDim.x * blockDim.x) >> 6;
    for (int row = wave; row < N_ROWS; row += nwaves) {
        int id = idx[row];
        float4 v = reinterpret_cast<const float4*>(C + (size_t)id * DIM)[lane];
        reinterpret_cast<float4*>(out + (size_t)row * DIM)[lane] = v;
        reinterpret_cast<float4*>(out + half + (size_t)row * DIM)[lane] = v;
    }
}

extern "C" void kernel_launch(void* const* d_in, const int* in_sizes, int n_in,
                              void* d_out, int out_size, void* d_ws, size_t ws_size,
                              hipStream_t stream) {
    const float* z  = (const float*)d_in[0];   // (32,1024,256) fp32
    const float* cb = (const float*)d_in[1];   // (8192,256)    fp32
    float* out = (float*)d_out;

    // big scratch in d_out (fully overwritten by gather at the end):
    char* sc = (char*)d_out;
    unsigned short* A2 = (unsigned short*)(sc);               // 33,554,432 B
    unsigned short* B2 = (unsigned short*)(sc + 33554432);    //  8,388,608 B
    float4* partials   = (float4*)(sc + 41943040);            // 16,777,216 B

    // small scratch in d_ws (~295 KB):
    float* csq    = (float*)d_ws;                              // 32 KB
    int*   idx    = (int*)((char*)d_ws + 32768);               // 128 KB
    int*   flags  = (int*)((char*)d_ws + 163840);              // 128 KB
    int*   count  = (int*)((char*)d_ws + 294912);              // 4 B

    static bool attr_done = false;
    if (!attr_done) {
        hipFuncSetAttribute((const void*)gemm_argmin_kernel,
                            hipFuncAttributeMaxDynamicSharedMemorySize, 131072);
        attr_done = true;
    }

    init_kernel<<<1, 1, 0, stream>>>(count);
    split_pack_kernel<<<(N_ROWS * DIM) / (256 * 8), 256, 0, stream>>>(z, A2);
    split_pack_kernel<<<(N_CODES * DIM) / (256 * 8), 256, 0, stream>>>(cb, B2);
    csq_kernel<<<(N_CODES * 64) / 256, 256, 0, stream>>>(cb, csq);
    gemm_argmin_kernel<<<4096, 512, 131072, stream>>>(A2, B2, csq, partials);
    reduce_kernel<<<N_ROWS / 256, 256, 0, stream>>>(partials, idx, flags, count);
    recheck_kernel<<<512, 256, 0, stream>>>(z, cb, csq, flags, count, idx);
    gather_kernel<<<2048, 256, 0, stream>>>(cb, idx, out);
}